// Round 4
// baseline (564.658 us; speedup 1.0000x reference)
//
#include <hip/hip_runtime.h>

#define SQ 2048
#define HD 1024
#define NB 8
#define NTOT (NB*SQ)

typedef _Float16 f16x8 __attribute__((ext_vector_type(8)));
typedef float f32x4 __attribute__((ext_vector_type(4)));
typedef short s16x8 __attribute__((ext_vector_type(8)));
typedef unsigned short u16;

__device__ __forceinline__ u16 f2h(float x){
  _Float16 h = (_Float16)x;
  u16 u; __builtin_memcpy(&u, &h, 2); return u;
}

// async global->LDS, 16B per lane; LDS dest = wave-uniform base + lane*16
#define STG(gp, lp) __builtin_amdgcn_global_load_lds( \
    (const __attribute__((address_space(1))) unsigned*)(gp), \
    (__attribute__((address_space(3))) unsigned*)(lp), 16, 0, 0)

// ---------------------------------------------------------------------------
// 256x128 f16 MFMA GEMM, BK=32, 4 waves (2x2), wave-tile 128x64 (8x4 frags).
// C = A[M,K] * B[N,K]^T, fp32 accum. 2-phase double-buffered LDS (T3-min):
//   per k-step: STAGE(next -> buf^1); ds_read(cur); 32 MFMA; barrier.
// Granule swizzle (16B granules, 4/row): stored q' = q ^ f(r),
// f(r) = (r&3)^((r>>2)&3)  -> ds_read_b128 is exactly 2-way (free).
// Write side is linear (global_load_lds); source address pre-swizzled.
// EPI 0: QKV. z=0:Q->f16, z=1:K->f16, z=2:V->fp32(d_out) + Vt f16[H,S]
// EPI 1: scores -> fp32, triangular grid over (256-row, 128-col) tiles
// EPI 2: PV + residual -> fp32, K trimmed to (bi+1)*256 keys
// ---------------------------------------------------------------------------
template<int EPI>
__global__ __launch_bounds__(256)
void gemm2(const u16* __restrict__ A, const u16* __restrict__ B,
           float* Cf, u16* Ch, u16* Vt,
           const float* __restrict__ b0, const float* __restrict__ b1,
           const float* __restrict__ b2,
           int K, int lda, int ldb, int ldc,
           long long sA, long long sB, long long sC)
{
  const int z = blockIdx.z;
  int bi = blockIdx.x, bj = blockIdx.y;
  if (EPI == 1){                      // triangular decode: t -> (i, j<2i+2)
    int t = bi;
    int i = (int)((sqrtf(4.f * (float)t + 1.f) - 1.f) * 0.5f);
    while ((i + 1) * (i + 2) <= t) ++i;
    while (i * (i + 1) > t) --i;
    bi = i;  bj = t - i * (i + 1);
  }

  A += (long long)z * sA;
  B += (long long)z * sB;

  // LDS: per buffer: A 256x32 f16 (8192 shorts) + B 128x32 (4096) = 24KB; x2
  __shared__ short lds[2 * 12288];

  const int tid  = threadIdx.x;
  const int lane = tid & 63, w = tid >> 6;
  const int wm = w >> 1, wn = w & 1;
  const int lrow = lane & 15, kgrp = lane >> 4;

  const long long rowA = (long long)bi * 256;
  const long long colB = (long long)bj * 128;

  // ---- staging setup: 4 A-granules + 2 B-granules (16B each) per thread ----
  const int l = lane;
  const int q = (l & 3) ^ ((l >> 2) & 3) ^ (l >> 4);   // source k-granule
  const int rsub = l >> 2;                             // row within 16-row strip

  const u16* gA[4];  const u16* gB[2];
  #pragma unroll
  for (int i = 0; i < 4; i++)
    gA[i] = A + (rowA + (w * 4 + i) * 16 + rsub) * (long long)lda + q * 8;
  #pragma unroll
  for (int i = 0; i < 2; i++)
    gB[i] = B + (colB + (w * 2 + i) * 16 + rsub) * (long long)ldb + q * 8;

  const int dA0 = (w * 4 + 0) * 512, dA1 = (w * 4 + 1) * 512;
  const int dA2 = (w * 4 + 2) * 512, dA3 = (w * 4 + 3) * 512;
  const int dB0 = 8192 + (w * 2 + 0) * 512, dB1 = 8192 + (w * 2 + 1) * 512;

  // ---- fragment read bases ----
  const int fl = (lrow & 3) ^ ((lrow >> 2) & 3);
  const int rdAoff = (wm * 128 + lrow) * 32 + ((kgrp ^ fl) << 3);          // +m*512
  const int rdBoff = 8192 + (wn * 64 + lrow) * 32 + ((kgrp ^ fl) << 3);    // +n*512

  f32x4 acc[8][4];
  const f32x4 zf = {0.f, 0.f, 0.f, 0.f};
  #pragma unroll
  for (int m = 0; m < 8; m++)
    #pragma unroll
    for (int n = 0; n < 4; n++) acc[m][n] = zf;

  int KT = K >> 5;
  if (EPI == 2){ int t = (bi + 1) * 8; if (t < KT) KT = t; }

#define STAGE_ALL(base) do {                                  \
    STG(gA[0], (base) + dA0);  STG(gA[1], (base) + dA1);      \
    STG(gA[2], (base) + dA2);  STG(gA[3], (base) + dA3);      \
    STG(gB[0], (base) + dB0);  STG(gB[1], (base) + dB1);      \
    gA[0] += 32; gA[1] += 32; gA[2] += 32; gA[3] += 32;       \
    gB[0] += 32; gB[1] += 32;                                 \
  } while (0)

  // prologue: stage k-step 0 into buf0
  STAGE_ALL(lds);
  __syncthreads();                      // drains vmcnt(0)

  int cur = 0;
  for (int kt = 0; kt < KT; ++kt){
    if (kt + 1 < KT) STAGE_ALL(lds + (cur ^ 1) * 12288);   // loads fly over MFMA

    const short* rA = lds + cur * 12288 + rdAoff;
    const short* rB = lds + cur * 12288 + rdBoff;
    f16x8 af[8];
    #pragma unroll
    for (int m = 0; m < 8; m++)
      af[m] = *(const f16x8*)(rA + m * 512);
    #pragma unroll
    for (int n = 0; n < 4; n++){
      f16x8 bf = *(const f16x8*)(rB + n * 512);
      #pragma unroll
      for (int m = 0; m < 8; m++)
        acc[m][n] = __builtin_amdgcn_mfma_f32_16x16x32_f16(af[m], bf, acc[m][n], 0, 0, 0);
    }

    __syncthreads();                    // vmcnt(0)+lgkmcnt(0)+barrier
    cur ^= 1;
  }
#undef STAGE_ALL

  // ---- epilogues ----
  if (EPI == 0){
    if (z < 2){
      u16* c = Ch + (long long)z * sC;
      const float* bias = z ? b1 : b0;
      #pragma unroll
      for (int n = 0; n < 4; n++){
        int col = (int)colB + wn * 64 + n * 16 + lrow;
        float ba = bias[col];
        #pragma unroll
        for (int m = 0; m < 8; m++){
          long long r = rowA + wm * 128 + m * 16 + kgrp * 4;
          #pragma unroll
          for (int j = 0; j < 4; j++)
            c[(r + j) * ldc + col] = f2h(acc[m][n][j] + ba);
        }
      }
    } else {
      // V: fp32 (+bias) into d_out, and transposed f16 into Vt[b][h][s]
      #pragma unroll
      for (int n = 0; n < 4; n++){
        int col = (int)colB + wn * 64 + n * 16 + lrow;
        float ba = b2[col];
        #pragma unroll
        for (int m = 0; m < 8; m++){
          long long r = rowA + wm * 128 + m * 16 + kgrp * 4;
          int bb = (int)(r >> 11);
          int s  = (int)(r & 2047);
          u16* vtc = Vt + ((long long)bb * HD + col) * SQ + s;
          #pragma unroll
          for (int j = 0; j < 4; j++){
            float v = acc[m][n][j] + ba;
            Cf[(r + j) * ldc + col] = v;
            vtc[j] = f2h(v);
          }
        }
      }
    }
  } else if (EPI == 1){
    float* cf = Cf + (long long)z * sC;
    #pragma unroll
    for (int n = 0; n < 4; n++){
      int col = (int)colB + wn * 64 + n * 16 + lrow;
      #pragma unroll
      for (int m = 0; m < 8; m++){
        long long r = rowA + wm * 128 + m * 16 + kgrp * 4;
        #pragma unroll
        for (int j = 0; j < 4; j++)
          cf[(r + j) * ldc + col] = acc[m][n][j];
      }
    }
  } else {
    float* cf = Cf + (long long)z * sC;
    #pragma unroll
    for (int n = 0; n < 4; n++){
      int col = (int)colB + wn * 64 + n * 16 + lrow;
      #pragma unroll
      for (int m = 0; m < 8; m++){
        long long r = rowA + wm * 128 + m * 16 + kgrp * 4;
        #pragma unroll
        for (int j = 0; j < 4; j++){
          long long o = (r + j) * ldc + col;
          cf[o] = acc[m][n][j] + cf[o];   // residual: read V then overwrite
        }
      }
    }
  }
}

// x fp32 -> f16 plane
__global__ __launch_bounds__(256)
void prep_x(const float* __restrict__ X, u16* __restrict__ Xh)
{
  const long long n8 = (long long)NTOT * HD / 8;
  for (long long i = (long long)blockIdx.x * 256 + threadIdx.x; i < n8;
       i += (long long)gridDim.x * 256){
    const float* p = X + i * 8;
    float4 a = *(const float4*)p;
    float4 b = *(const float4*)(p + 4);
    float f[8] = {a.x, a.y, a.z, a.w, b.x, b.y, b.z, b.w};
    s16x8 h;
    #pragma unroll
    for (int j = 0; j < 8; j++) h[j] = (short)f2h(f[j]);
    *(s16x8*)&Xh[i * 8] = h;
  }
}

// W[k][n] -> transposed f16 Wt[z][n][k]
__global__ void prep_w(const float* __restrict__ Wq, const float* __restrict__ Wk,
                       const float* __restrict__ Wv, u16* __restrict__ Wt)
{
  __shared__ float t[32][33];
  const float* Win = (blockIdx.z == 0) ? Wq : (blockIdx.z == 1) ? Wk : Wv;
  const size_t zo = (size_t)blockIdx.z * HD * HD;
  int n0 = blockIdx.x * 32, k0 = blockIdx.y * 32;
  int tx = threadIdx.x, ty = threadIdx.y;
  #pragma unroll
  for (int i = 0; i < 4; i++)
    t[ty + 8*i][tx] = Win[(size_t)(k0 + ty + 8*i) * HD + n0 + tx];
  __syncthreads();
  #pragma unroll
  for (int i = 0; i < 4; i++)
    Wt[zo + (size_t)(n0 + ty + 8*i) * HD + k0 + tx] = f2h(t[tx][ty + 8*i]);
}

__global__ __launch_bounds__(256)
void softmax_causal(const float* __restrict__ SC, u16* __restrict__ P)
{
  const int s = blockIdx.x;
  const long long zoff = (long long)blockIdx.y * SQ * SQ;
  const float* row = SC + zoff + (long long)s * SQ;
  u16* prow = P + zoff + (long long)s * SQ;

  __shared__ float buf[SQ];
  __shared__ float red[4];
  const int tid = threadIdx.x, lane = tid & 63, wid = tid >> 6;

  float m = -3.4e38f;
  for (int t = tid; t <= s; t += 256){ float v = row[t]; buf[t] = v; m = fmaxf(m, v); }
  #pragma unroll
  for (int o = 32; o; o >>= 1) m = fmaxf(m, __shfl_xor(m, o));
  if (lane == 0) red[wid] = m;
  __syncthreads();
  m = fmaxf(fmaxf(red[0], red[1]), fmaxf(red[2], red[3]));
  __syncthreads();

  float sum = 0.f;
  for (int t = tid; t <= s; t += 256){ float e = __expf(buf[t] - m); buf[t] = e; sum += e; }
  #pragma unroll
  for (int o = 32; o; o >>= 1) sum += __shfl_xor(sum, o);
  if (lane == 0) red[wid] = sum;
  __syncthreads();
  sum = red[0] + red[1] + red[2] + red[3];
  const float inv = 1.f / sum;

  const int lim = ((s >> 8) + 1) << 8;   // PV reads keys < ceil256(s+1)
  for (int t = tid; t < lim; t += 256)
    prow[t] = (t <= s) ? f2h(buf[t] * inv) : (u16)0;
}

__global__ __launch_bounds__(256)
void layernorm_inplace(float* __restrict__ Y, const float* __restrict__ gamma,
                       const float* __restrict__ beta)
{
  float* y = Y + (long long)blockIdx.x * HD;
  const int tid = threadIdx.x, lane = tid & 63, wid = tid >> 6;
  float xv[4];
  float s = 0.f, ss = 0.f;
  #pragma unroll
  for (int i = 0; i < 4; i++){
    float v = y[tid + i * 256];
    xv[i] = v; s += v; ss += v * v;
  }
  #pragma unroll
  for (int o = 32; o; o >>= 1){ s += __shfl_xor(s, o); ss += __shfl_xor(ss, o); }
  __shared__ float r1[4], r2[4];
  if (lane == 0){ r1[wid] = s; r2[wid] = ss; }
  __syncthreads();
  s  = r1[0] + r1[1] + r1[2] + r1[3];
  ss = r2[0] + r2[1] + r2[2] + r2[3];
  const float mu   = s * (1.f / HD);
  const float var  = ss * (1.f / HD) - mu * mu;
  const float rstd = rsqrtf(var + 1e-5f);
  #pragma unroll
  for (int i = 0; i < 4; i++){
    int c = tid + i * 256;
    y[c] = (xv[i] - mu) * rstd * gamma[c] + beta[c];
  }
}

extern "C" void kernel_launch(void* const* d_in, const int* in_sizes, int n_in,
                              void* d_out, int out_size, void* d_ws, size_t ws_size,
                              hipStream_t stream)
{
  const float* x     = (const float*)d_in[0];
  const float* Wq    = (const float*)d_in[1];
  const float* bq    = (const float*)d_in[2];
  const float* Wk    = (const float*)d_in[3];
  const float* bk    = (const float*)d_in[4];
  const float* Wv    = (const float*)d_in[5];
  const float* bv    = (const float*)d_in[6];
  const float* gamma = (const float*)d_in[7];
  const float* beta  = (const float*)d_in[8];
  float* out = (float*)d_out;

  char* wsp = (char*)d_ws;
  size_t off = 0;
  auto alloc = [&](size_t bytes) -> char* {
    char* p = wsp + off;
    off = (off + bytes + 255) & ~(size_t)255;
    return p;
  };

  u16* Wt = (u16*)alloc(3ULL * HD * HD * 2);          // 6.3 MB  (transposed f16)
  u16* QK = (u16*)alloc(2ULL * NTOT * HD * 2);        // 67.1 MB (Q plane, K plane)
  u16* Vt = (u16*)alloc((size_t)NB * HD * SQ * 2);    // 33.6 MB (V transposed f16)

  // region: xh (phase A) aliased with SC/P (phase B); both dead across phases
  size_t rem = (ws_size > off) ? (ws_size - off) : 0;
  int G = (int)(rem / ((size_t)SQ * SQ * 6));
  if (G > NB) G = NB;
  if (G < 1)  G = 1;
  u16*   xh = (u16*)(wsp + off);                      // 33.5 MB
  float* SC = (float*)(wsp + off);                    // G * 16.8 MB
  u16*   P  = (u16*)(wsp + off + (size_t)G * SQ * SQ * 4);  // G * 8.4 MB

  u16* Qh = QK;
  u16* Kh = QK + (size_t)NTOT * HD;
  float* V = out;   // V fp32 lives in d_out; PV reads V[o] then overwrites o

  prep_x<<<dim3(2048), dim3(256), 0, stream>>>(x, xh);
  prep_w<<<dim3(HD/32, HD/32, 3), dim3(32, 8), 0, stream>>>(Wq, Wk, Wv, Wt);

  // QKV projection: z=0 -> Q f16, z=1 -> K f16, z=2 -> V fp32(d_out) + Vt f16
  gemm2<0><<<dim3(NTOT/256, HD/128, 3), 256, 0, stream>>>(
      xh, Wt, V, QK, Vt, bq, bk, bv,
      HD, HD, HD, HD,
      0LL, (long long)HD * HD, (long long)NTOT * HD);

  for (int g0 = 0; g0 < NB; g0 += G){
    int g = (G < NB - g0) ? G : (NB - g0);
    // scores: triangular grid, 72 tiles of 256x128 per batch
    gemm2<1><<<dim3(72, 1, g), 256, 0, stream>>>(
        Qh + (size_t)g0 * SQ * HD, Kh + (size_t)g0 * SQ * HD,
        SC, nullptr, nullptr, nullptr, nullptr, nullptr,
        HD, HD, HD, SQ,
        (long long)SQ * HD, (long long)SQ * HD, (long long)SQ * SQ);
    softmax_causal<<<dim3(SQ, g), 256, 0, stream>>>(SC, P);
    // PV + residual
    gemm2<2><<<dim3(SQ/256, HD/128, g), 256, 0, stream>>>(
        P, Vt + (size_t)g0 * HD * SQ,
        out + (size_t)g0 * SQ * HD, nullptr, nullptr, nullptr, nullptr, nullptr,
        SQ, SQ, SQ, HD,
        (long long)SQ * SQ, (long long)HD * SQ, (long long)SQ * HD);
  }

  layernorm_inplace<<<dim3(NTOT), 256, 0, stream>>>(out, gamma, beta);
}

// Round 5
// 510.518 us; speedup vs baseline: 1.1061x; 1.1061x over previous
//
#include <hip/hip_runtime.h>

#define SQ 2048
#define HD 1024
#define NB 8
#define NTOT (NB*SQ)
#define NTILE 16        // SQ/128
#define NTRI 136        // NTILE*(NTILE+1)/2
#define CE (NTRI*16384) // compact score elems per batch

typedef _Float16 f16x8 __attribute__((ext_vector_type(8)));
typedef float f32x4 __attribute__((ext_vector_type(4)));
typedef short s16x8 __attribute__((ext_vector_type(8)));
typedef unsigned short u16;

__device__ __forceinline__ u16 f2h(float x){
  _Float16 h = (_Float16)x;
  u16 u; __builtin_memcpy(&u, &h, 2); return u;
}

// async global->LDS, 16B per lane; LDS dest = wave-uniform base + lane*16
#define STG(gp, lp) __builtin_amdgcn_global_load_lds( \
    (const __attribute__((address_space(1))) unsigned*)(gp), \
    (__attribute__((address_space(3))) unsigned*)(lp), 16, 0, 0)

// ---------------------------------------------------------------------------
// 128x128 f16 MFMA GEMM (round-3 proven core), BK=32, 4 waves (2x2).
// C = A[M,K]*B[N,K]^T, fp32 accum. global_load_lds staging, granule-XOR
// swizzle (LDS granule (r,c) holds global (r, c^(r&3))).
// EPI 0: QKV. grid (bj, bi, z): consecutive blocks share A-tile -> L2 hits.
//        z=0:Q->f16, z=1:K->f16, z=2:V->fp32(d_out) + Vt f16[H,S]
// EPI 1: scores -> fp32 COMPACT triangular tiles (tile t at Cf + t*16384)
// EPI 2: PV + residual; A = compact P tiles; bi reversed for tail balance
// ---------------------------------------------------------------------------
template<int EPI>
__global__ __launch_bounds__(256)
void gemm_f16(const u16* __restrict__ A, const u16* __restrict__ B,
              float* Cf, u16* Ch, u16* Vt,
              const float* __restrict__ b0, const float* __restrict__ b1,
              const float* __restrict__ b2,
              int K, int lda, int ldb, int ldc,
              long long sA, long long sB, long long sC)
{
  const int z = blockIdx.z;
  int bi, bj, tri = 0;
  if (EPI == 0){ bi = blockIdx.y; bj = blockIdx.x; }
  else if (EPI == 1){                  // triangular decode: t -> (i, j<=i)
    int t = blockIdx.x;
    int i = (int)((sqrtf(8.f * (float)t + 1.f) - 1.f) * 0.5f);
    while ((i + 1) * (i + 2) / 2 <= t) ++i;
    while (i * (i + 1) / 2 > t) --i;
    bi = i;  bj = t - i * (i + 1) / 2;  tri = t;
  } else {                             // PV: reverse row tiles (long first)
    bi = (int)(gridDim.x - 1 - blockIdx.x);  bj = blockIdx.y;
    tri = bi * (bi + 1) / 2;
  }

  if (EPI != 2) A += (long long)z * sA;
  B += (long long)z * sB;

  __shared__ short lds[2 * 4096];      // A tile 128x32, B tile 128x32 (f16)

  const int tid  = threadIdx.x;
  const int lane = tid & 63, w = tid >> 6;
  const int wm = w >> 1, wn = w & 1;
  const int lrow = lane & 15, kgrp = lane >> 4;

  const long long rowA = (long long)bi * 128;
  const long long rowB = (long long)bj * 128;

  // staging: 4 granules (16B) per thread (2 for A, 2 for B)
  const int q0 = w * 128 + lane, q1 = q0 + 64;
  const int r0s = q0 >> 2, r1s = q1 >> 2;
  const int kq0 = (q0 & 3) ^ (r0s & 3), kq1 = (q1 & 3) ^ (r1s & 3);

  const u16 *gA0, *gA1;
  if (EPI == 2){
    // A = compact P tiles: base + tile(kt>>2)*16384 + r*128 + (kt&3)*32 + kq*8
    const u16* Pb = A + (long long)z * sA + (long long)tri * 16384;
    gA0 = Pb + r0s * 128 + kq0 * 8;
    gA1 = Pb + r1s * 128 + kq1 * 8;
  } else {
    gA0 = A + (rowA + r0s) * (long long)lda + kq0 * 8;
    gA1 = A + (rowA + r1s) * (long long)lda + kq1 * 8;
  }
  const u16* gB0 = B + (rowB + r0s) * (long long)ldb + kq0 * 8;
  const u16* gB1 = B + (rowB + r1s) * (long long)ldb + kq1 * 8;

  short* lA0 = lds + (w * 2 + 0) * 512;
  short* lA1 = lds + (w * 2 + 1) * 512;
  short* lB0 = lds + 4096 + (w * 2 + 0) * 512;
  short* lB1 = lds + 4096 + (w * 2 + 1) * 512;

  // fragment read bases (swizzle-matched)
  const int kqr8 = ((kgrp ^ (lrow & 3)) << 3);
  const short* rdA = lds +        ((wm * 64 + lrow) << 5) + kqr8;   // + m*512
  const short* rdB = lds + 4096 + ((wn * 64 + lrow) << 5) + kqr8;   // + n*512

  f32x4 acc[4][4];
  const f32x4 zf = {0.f, 0.f, 0.f, 0.f};
  #pragma unroll
  for (int m = 0; m < 4; m++)
    #pragma unroll
    for (int n = 0; n < 4; n++) acc[m][n] = zf;

  int KT = K >> 5;
  if (EPI == 2){ int t = (bi + 1) * 4; if (t < KT) KT = t; }

  for (int kt = 0; kt < KT; ++kt){
    __syncthreads();                   // prev-tile readers done
    STG(gA0, lA0);  STG(gA1, lA1);
    STG(gB0, lB0);  STG(gB1, lB1);
    if (EPI == 2){
      int adv = ((kt & 3) == 3) ? (16384 - 96) : 32;   // tile-hop in compact P
      gA0 += adv; gA1 += adv;
    } else {
      gA0 += 32; gA1 += 32;
    }
    gB0 += 32; gB1 += 32;
    __syncthreads();                   // includes vmcnt(0) drain

    f16x8 af[4];
    #pragma unroll
    for (int m = 0; m < 4; m++)
      af[m] = *(const f16x8*)(rdA + m * 512);
    #pragma unroll
    for (int n = 0; n < 4; n++){
      f16x8 bf = *(const f16x8*)(rdB + n * 512);
      #pragma unroll
      for (int m = 0; m < 4; m++)
        acc[m][n] = __builtin_amdgcn_mfma_f32_16x16x32_f16(af[m], bf, acc[m][n], 0, 0, 0);
    }
  }

  // ---- epilogues ----
  if (EPI == 0){
    if (z < 2){
      u16* c = Ch + (long long)z * sC;
      const float* bias = z ? b1 : b0;
      #pragma unroll
      for (int n = 0; n < 4; n++){
        int col = (int)rowB + wn * 64 + n * 16 + lrow;
        float ba = bias[col];
        #pragma unroll
        for (int m = 0; m < 4; m++){
          long long r = rowA + wm * 64 + m * 16 + kgrp * 4;
          #pragma unroll
          for (int j = 0; j < 4; j++)
            c[(r + j) * ldc + col] = f2h(acc[m][n][j] + ba);
        }
      }
    } else {
      // V: fp32 (+bias) into d_out, and transposed f16 into Vt[b][h][s]
      const int bb = (int)(rowA >> 11);
      u16* vtb = Vt + (long long)bb * HD * SQ;
      #pragma unroll
      for (int n = 0; n < 4; n++){
        int col = (int)rowB + wn * 64 + n * 16 + lrow;
        float ba = b2[col];
        u16* vtc = vtb + (long long)col * SQ;
        #pragma unroll
        for (int m = 0; m < 4; m++){
          long long r = rowA + wm * 64 + m * 16 + kgrp * 4;
          int s = (int)(r & 2047);
          #pragma unroll
          for (int j = 0; j < 4; j++){
            float v = acc[m][n][j] + ba;
            Cf[(r + j) * ldc + col] = v;
            vtc[s + j] = f2h(v);
          }
        }
      }
    }
  } else if (EPI == 1){
    // compact tile store: tile 'tri', row-local r, col-local c, ld=128
    float* cf = Cf + (long long)z * sC + (long long)tri * 16384;
    #pragma unroll
    for (int n = 0; n < 4; n++){
      int col = wn * 64 + n * 16 + lrow;
      #pragma unroll
      for (int m = 0; m < 4; m++){
        int r = wm * 64 + m * 16 + kgrp * 4;
        #pragma unroll
        for (int j = 0; j < 4; j++)
          cf[(r + j) * 128 + col] = acc[m][n][j];
      }
    }
  } else {
    float* cf = Cf + (long long)z * sC;
    #pragma unroll
    for (int n = 0; n < 4; n++){
      int col = (int)rowB + wn * 64 + n * 16 + lrow;
      #pragma unroll
      for (int m = 0; m < 4; m++){
        long long r = rowA + wm * 64 + m * 16 + kgrp * 4;
        #pragma unroll
        for (int j = 0; j < 4; j++){
          long long o = (r + j) * ldc + col;
          cf[o] = acc[m][n][j] + cf[o];   // residual: read V then overwrite
        }
      }
    }
  }
}

// x fp32 -> f16 plane
__global__ __launch_bounds__(256)
void prep_x(const float* __restrict__ X, u16* __restrict__ Xh)
{
  const long long n8 = (long long)NTOT * HD / 8;
  for (long long i = (long long)blockIdx.x * 256 + threadIdx.x; i < n8;
       i += (long long)gridDim.x * 256){
    const float* p = X + i * 8;
    float4 a = *(const float4*)p;
    float4 b = *(const float4*)(p + 4);
    float f[8] = {a.x, a.y, a.z, a.w, b.x, b.y, b.z, b.w};
    s16x8 h;
    #pragma unroll
    for (int j = 0; j < 8; j++) h[j] = (short)f2h(f[j]);
    *(s16x8*)&Xh[i * 8] = h;
  }
}

// W[k][n] -> transposed f16 Wt[z][n][k]
__global__ void prep_w(const float* __restrict__ Wq, const float* __restrict__ Wk,
                       const float* __restrict__ Wv, u16* __restrict__ Wt)
{
  __shared__ float t[32][33];
  const float* Win = (blockIdx.z == 0) ? Wq : (blockIdx.z == 1) ? Wk : Wv;
  const size_t zo = (size_t)blockIdx.z * HD * HD;
  int n0 = blockIdx.x * 32, k0 = blockIdx.y * 32;
  int tx = threadIdx.x, ty = threadIdx.y;
  #pragma unroll
  for (int i = 0; i < 4; i++)
    t[ty + 8*i][tx] = Win[(size_t)(k0 + ty + 8*i) * HD + n0 + tx];
  __syncthreads();
  #pragma unroll
  for (int i = 0; i < 4; i++)
    Wt[zo + (size_t)(n0 + ty + 8*i) * HD + k0 + tx] = f2h(t[tx][ty + 8*i]);
}

// softmax over compact triangular SC -> compact P (f16)
__global__ __launch_bounds__(256)
void softmax_causal(const float* __restrict__ SC, u16* __restrict__ P)
{
  const int s = blockIdx.x;
  const int i = s >> 7;                 // row tile
  const int tri = i * (i + 1) / 2;
  const int rowoff = (s & 127) * 128;
  const float* scb = SC + (long long)blockIdx.y * CE + (long long)tri * 16384 + rowoff;
  u16* pb = P + (long long)blockIdx.y * CE + (long long)tri * 16384 + rowoff;

  __shared__ float buf[SQ];
  __shared__ float red[4];
  const int tid = threadIdx.x, lane = tid & 63, wid = tid >> 6;

  float m = -3.4e38f;
  for (int t = tid; t <= s; t += 256){
    float v = scb[(t >> 7) * 16384 + (t & 127)];
    buf[t] = v; m = fmaxf(m, v);
  }
  #pragma unroll
  for (int o = 32; o; o >>= 1) m = fmaxf(m, __shfl_xor(m, o));
  if (lane == 0) red[wid] = m;
  __syncthreads();
  m = fmaxf(fmaxf(red[0], red[1]), fmaxf(red[2], red[3]));
  __syncthreads();

  float sum = 0.f;
  for (int t = tid; t <= s; t += 256){ float e = __expf(buf[t] - m); buf[t] = e; sum += e; }
  #pragma unroll
  for (int o = 32; o; o >>= 1) sum += __shfl_xor(sum, o);
  if (lane == 0) red[wid] = sum;
  __syncthreads();
  sum = red[0] + red[1] + red[2] + red[3];
  const float inv = 1.f / sum;

  const int lim = (i + 1) << 7;         // PV reads keys < (i+1)*128
  for (int t = tid; t < lim; t += 256)
    pb[(t >> 7) * 16384 + (t & 127)] = (t <= s) ? f2h(buf[t] * inv) : (u16)0;
}

__global__ __launch_bounds__(256)
void layernorm_inplace(float* __restrict__ Y, const float* __restrict__ gamma,
                       const float* __restrict__ beta)
{
  float* y = Y + (long long)blockIdx.x * HD;
  const int tid = threadIdx.x, lane = tid & 63, wid = tid >> 6;
  float xv[4];
  float s = 0.f, ss = 0.f;
  #pragma unroll
  for (int i = 0; i < 4; i++){
    float v = y[tid + i * 256];
    xv[i] = v; s += v; ss += v * v;
  }
  #pragma unroll
  for (int o = 32; o; o >>= 1){ s += __shfl_xor(s, o); ss += __shfl_xor(ss, o); }
  __shared__ float r1[4], r2[4];
  if (lane == 0){ r1[wid] = s; r2[wid] = ss; }
  __syncthreads();
  s  = r1[0] + r1[1] + r1[2] + r1[3];
  ss = r2[0] + r2[1] + r2[2] + r2[3];
  const float mu   = s * (1.f / HD);
  const float var  = ss * (1.f / HD) - mu * mu;
  const float rstd = rsqrtf(var + 1e-5f);
  #pragma unroll
  for (int i = 0; i < 4; i++){
    int c = tid + i * 256;
    y[c] = (xv[i] - mu) * rstd * gamma[c] + beta[c];
  }
}

extern "C" void kernel_launch(void* const* d_in, const int* in_sizes, int n_in,
                              void* d_out, int out_size, void* d_ws, size_t ws_size,
                              hipStream_t stream)
{
  const float* x     = (const float*)d_in[0];
  const float* Wq    = (const float*)d_in[1];
  const float* bq    = (const float*)d_in[2];
  const float* Wk    = (const float*)d_in[3];
  const float* bk    = (const float*)d_in[4];
  const float* Wv    = (const float*)d_in[5];
  const float* bv    = (const float*)d_in[6];
  const float* gamma = (const float*)d_in[7];
  const float* beta  = (const float*)d_in[8];
  float* out = (float*)d_out;

  char* wsp = (char*)d_ws;
  size_t off = 0;
  auto alloc = [&](size_t bytes) -> char* {
    char* p = wsp + off;
    off = (off + bytes + 255) & ~(size_t)255;
    return p;
  };

  u16* Wt = (u16*)alloc(3ULL * HD * HD * 2);          // 6.3 MB  (transposed f16)
  u16* QK = (u16*)alloc(2ULL * NTOT * HD * 2);        // 67.1 MB (Q plane, K plane)
  u16* Vt = (u16*)alloc((size_t)NB * HD * SQ * 2);    // 33.6 MB (V transposed f16)

  // region: xh (phase A) aliased with compact SC/P (phase B)
  size_t rem = (ws_size > off) ? (ws_size - off) : 0;
  size_t perb = (size_t)CE * 6;                       // SC f32 + P f16 per batch
  int G = (int)(rem / perb);
  if (G > NB) G = NB;
  if (G < 1)  G = 1;
  u16*   xh = (u16*)(wsp + off);                      // 33.5 MB
  float* SC = (float*)(wsp + off);                    // G * 8.9 MB (compact)
  u16*   P  = (u16*)(wsp + off + (size_t)G * CE * 4); // G * 4.5 MB (compact)

  u16* Qh = QK;
  u16* Kh = QK + (size_t)NTOT * HD;
  float* V = out;   // V fp32 lives in d_out; PV reads V[o] then overwrites o

  prep_x<<<dim3(2048), dim3(256), 0, stream>>>(x, xh);
  prep_w<<<dim3(HD/32, HD/32, 3), dim3(32, 8), 0, stream>>>(Wq, Wk, Wv, Wt);

  // QKV projection, grid (bj, bi, z): A-tile reuse across consecutive blocks
  gemm_f16<0><<<dim3(HD/128, NTOT/128, 3), 256, 0, stream>>>(
      xh, Wt, V, QK, Vt, bq, bk, bv,
      HD, HD, HD, HD,
      0LL, (long long)HD * HD, (long long)NTOT * HD);

  for (int g0 = 0; g0 < NB; g0 += G){
    int g = (G < NB - g0) ? G : (NB - g0);
    // scores: triangular compact, 136 tiles of 128x128 per batch
    gemm_f16<1><<<dim3(NTRI, 1, g), 256, 0, stream>>>(
        Qh + (size_t)g0 * SQ * HD, Kh + (size_t)g0 * SQ * HD,
        SC, nullptr, nullptr, nullptr, nullptr, nullptr,
        HD, HD, HD, 128,
        (long long)SQ * HD, (long long)SQ * HD, (long long)CE);
    softmax_causal<<<dim3(SQ, g), 256, 0, stream>>>(SC, P);
    // PV + residual; A = compact P
    gemm_f16<2><<<dim3(NTILE, HD/128, g), 256, 0, stream>>>(
        P, Vt + (size_t)g0 * HD * SQ,
        out + (size_t)g0 * SQ * HD, nullptr, nullptr, nullptr, nullptr, nullptr,
        SQ, 128, SQ, HD,
        (long long)CE, (long long)HD * SQ, (long long)SQ * HD);
  }

  layernorm_inplace<<<dim3(NTOT), 256, 0, stream>>>(out, gamma, beta);
}

// Round 6
// 379.590 us; speedup vs baseline: 1.4875x; 1.3449x over previous
//
#include <hip/hip_runtime.h>

#define SQ 2048
#define HD 1024
#define NB 8
#define NTOT (NB*SQ)
#define NT2 8           // SQ/256
#define NTRI2 36        // NT2*(NT2+1)/2
#define CE ((long long)NTRI2*65536)  // compact score elems per batch (256x256 tiles)

typedef _Float16 f16x8 __attribute__((ext_vector_type(8)));
typedef float f32x4 __attribute__((ext_vector_type(4)));
typedef short s16x8 __attribute__((ext_vector_type(8)));
typedef unsigned short u16;

__device__ __forceinline__ u16 f2h(float x){
  _Float16 h = (_Float16)x;
  u16 u; __builtin_memcpy(&u, &h, 2); return u;
}

// async global->LDS: dest is wave-uniform base, HW adds lane*16
#define STG(gp, lp) __builtin_amdgcn_global_load_lds( \
    (const __attribute__((address_space(1))) unsigned*)(gp), \
    (__attribute__((address_space(3))) unsigned*)(lp), 16, 0, 0)

// ---------------------------------------------------------------------------
// 256x256 f16 MFMA GEMM, BK=64, 8 waves (2M x 4N), wave tile 128x64.
// Pipelined: stage K-tile kt+1 into buf^1 at top of iter kt (loads in flight
// across 4 raw-s_barrier phases of MFMA), single vmcnt drain per K-tile via
// __syncthreads at iter bottom. Granule-XOR swizzle: LDS granule (r,g) holds
// global (r, g^(r&7)) -> ds_read_b128 fragments are bank-minimum.
// EPI 0: QKV. z=0:Q->f16, z=1:K->f16, z=2:V->fp32(d_out) + Vt f16[H,S]
// EPI 1: scores -> fp32 compact triangular 256^2 tiles (t = tri index)
// EPI 2: PV + residual; A = compact P tiles; K trimmed to (bi+1)*256
// ---------------------------------------------------------------------------
template<int EPI>
__global__ __launch_bounds__(512, 2)
void gemm8(const u16* __restrict__ A, const u16* __restrict__ B,
           float* Cf, u16* Ch, u16* Vt,
           const float* __restrict__ b0, const float* __restrict__ b1,
           const float* __restrict__ b2,
           int K, int lda, int ldb, int ldc,
           long long sA, long long sB, long long sC)
{
  const int z = blockIdx.z;
  int bi, bj, tri = 0;
  if (EPI == 1){                       // triangular decode: t -> (i, j<=i)
    int t = blockIdx.x;
    int i = (int)((sqrtf(8.f * (float)t + 1.f) - 1.f) * 0.5f);
    while ((i + 1) * (i + 2) / 2 <= t) ++i;
    while (i * (i + 1) / 2 > t) --i;
    bi = i;  bj = t - i * (i + 1) / 2;  tri = t;
  } else {
    bi = blockIdx.x;  bj = blockIdx.y;
    if (EPI == 2) tri = bi * (bi + 1) / 2;
  }

  __shared__ short lds[65536];         // 2 bufs x (A 256x64 + B 256x64) f16

  const int tid  = threadIdx.x;
  const int lane = tid & 63, w = tid >> 6;
  const int wm2 = w >> 2, wn4 = w & 3;
  const int lrow = lane & 15, kgrp = lane >> 4;

  const long long rowA = (long long)bi * 256;
  const long long colB = (long long)bj * 256;

  // ---- staging sources: 4 insts per operand, 16B/lane, pre-swizzled ----
  const int rt = tid >> 3;                       // 0..63: row within 64-row strip
  const int gs = (tid & 7) ^ (rt & 7);           // swizzled source granule

  const u16 *sAp[4], *sBp[4];
  if (EPI == 2){
    const u16* Pb = A + (long long)z * sA + (long long)tri * 65536;
    #pragma unroll
    for (int i = 0; i < 4; i++)
      sAp[i] = Pb + (i * 64 + rt) * 256 + gs * 8;      // tile 0, ld=256
  } else {
    const u16* Ab = A + (EPI == 0 ? 0LL : (long long)z * sA);
    #pragma unroll
    for (int i = 0; i < 4; i++)
      sAp[i] = Ab + (rowA + i * 64 + rt) * (long long)lda + gs * 8;
  }
  {
    const u16* Bb = B + (long long)z * sB;
    #pragma unroll
    for (int i = 0; i < 4; i++)
      sBp[i] = Bb + (colB + i * 64 + rt) * (long long)ldb + gs * 8;
  }

  // wave-uniform LDS dest bases (shorts): inst i of A / B in buffer `buf`
  #define ADST(buf,i) (lds + (buf) * 32768 +         (i) * 4096 + w * 512)
  #define BDST(buf,i) (lds + (buf) * 32768 + 16384 + (i) * 4096 + w * 512)

  // ---- fragment read offsets (shorts), swizzle-matched ----
  const int fl = lrow & 7;
  const int swzk[2] = { ((0 + kgrp) ^ fl) * 8, ((4 + kgrp) ^ fl) * 8 };
  const int arow = (wm2 * 128 + lrow) * 64;      // + m*1024
  const int brow = 16384 + (wn4 * 64 + lrow) * 64;   // + n*1024

  f32x4 acc[8][4];
  const f32x4 zf = {0.f, 0.f, 0.f, 0.f};
  #pragma unroll
  for (int m = 0; m < 8; m++)
    #pragma unroll
    for (int n = 0; n < 4; n++) acc[m][n] = zf;

  int KT = K >> 6;
  if (EPI == 2){ int t = (bi + 1) * 4; if (t < KT) KT = t; }

  // advance staging pointers past just-staged tile tS -> tS+1
  auto advance = [&](int tS){
    long long advA = 64;
    if (EPI == 2) advA = ((tS & 3) == 3) ? (65536 - 192) : 64;
    #pragma unroll
    for (int i = 0; i < 4; i++){ sAp[i] += advA; sBp[i] += 64; }
  };

  // prologue: stage tile 0 into buf0
  #pragma unroll
  for (int i = 0; i < 4; i++) STG(sAp[i], ADST(0, i));
  #pragma unroll
  for (int i = 0; i < 4; i++) STG(sBp[i], BDST(0, i));
  advance(0);
  __syncthreads();

  int cur = 0;
  for (int kt = 0; kt < KT; ++kt){
    const bool pf = (kt + 1 < KT);
    const short* Ab = lds + cur * 32768;
    const int nb = cur ^ 1;

    #pragma unroll
    for (int qm = 0; qm < 2; qm++){
      f16x8 aq[4][2];
      #pragma unroll
      for (int m4 = 0; m4 < 4; m4++)
        #pragma unroll
        for (int ks = 0; ks < 2; ks++)
          aq[m4][ks] = *(const f16x8*)(Ab + arow + (qm * 4 + m4) * 1024 + swzk[ks]);

      #pragma unroll
      for (int qn = 0; qn < 2; qn++){
        // prefetch next K-tile: A-insts at phase 0, B-insts at phase 1
        if (pf && qm == 0 && qn == 0){
          #pragma unroll
          for (int i = 0; i < 4; i++) STG(sAp[i], ADST(nb, i));
        }
        if (pf && qm == 0 && qn == 1){
          #pragma unroll
          for (int i = 0; i < 4; i++) STG(sBp[i], BDST(nb, i));
        }
        f16x8 bq[2][2];
        #pragma unroll
        for (int n2 = 0; n2 < 2; n2++)
          #pragma unroll
          for (int ks = 0; ks < 2; ks++)
            bq[n2][ks] = *(const f16x8*)(Ab + brow + (qn * 2 + n2) * 1024 + swzk[ks]);

        __builtin_amdgcn_s_setprio(1);
        #pragma unroll
        for (int n2 = 0; n2 < 2; n2++)
          #pragma unroll
          for (int m4 = 0; m4 < 4; m4++)
            #pragma unroll
            for (int ks = 0; ks < 2; ks++)
              acc[qm * 4 + m4][qn * 2 + n2] =
                __builtin_amdgcn_mfma_f32_16x16x32_f16(aq[m4][ks], bq[n2][ks],
                                                       acc[qm * 4 + m4][qn * 2 + n2], 0, 0, 0);
        __builtin_amdgcn_s_setprio(0);
        __builtin_amdgcn_s_barrier();        // raw phase barrier (no drain)
      }
    }
    if (pf) advance(kt + 1);
    __syncthreads();                         // once-per-K-tile vmcnt drain + fence
    cur ^= 1;
  }
  #undef ADST
  #undef BDST

  // ---- epilogues ----
  if (EPI == 0){
    if (z < 2){
      u16* c = Ch + (long long)z * sC;
      const float* bias = z ? b1 : b0;
      #pragma unroll
      for (int n = 0; n < 4; n++){
        int col = (int)colB + wn4 * 64 + n * 16 + lrow;
        float ba = bias[col];
        #pragma unroll
        for (int m = 0; m < 8; m++){
          long long r = rowA + wm2 * 128 + m * 16 + kgrp * 4;
          #pragma unroll
          for (int j = 0; j < 4; j++)
            c[(r + j) * ldc + col] = f2h(acc[m][n][j] + ba);
        }
      }
    } else {
      #pragma unroll
      for (int n = 0; n < 4; n++){
        int col = (int)colB + wn4 * 64 + n * 16 + lrow;
        float ba = b2[col];
        #pragma unroll
        for (int m = 0; m < 8; m++){
          long long r = rowA + wm2 * 128 + m * 16 + kgrp * 4;
          int bb = (int)(r >> 11);
          int s  = (int)(r & 2047);
          u16* vtc = Vt + ((long long)bb * HD + col) * SQ + s;
          #pragma unroll
          for (int j = 0; j < 4; j++){
            float v = acc[m][n][j] + ba;
            Cf[(r + j) * ldc + col] = v;
            vtc[j] = f2h(v);
          }
        }
      }
    }
  } else if (EPI == 1){
    // compact 256x256 tile store, ld=256
    float* cf = Cf + (long long)z * sC + (long long)tri * 65536;
    #pragma unroll
    for (int n = 0; n < 4; n++){
      int col = wn4 * 64 + n * 16 + lrow;
      #pragma unroll
      for (int m = 0; m < 8; m++){
        int r = wm2 * 128 + m * 16 + kgrp * 4;
        #pragma unroll
        for (int j = 0; j < 4; j++)
          cf[(r + j) * 256 + col] = acc[m][n][j];
      }
    }
  } else {
    float* cf = Cf + (long long)z * sC;
    #pragma unroll
    for (int n = 0; n < 4; n++){
      int col = (int)colB + wn4 * 64 + n * 16 + lrow;
      #pragma unroll
      for (int m = 0; m < 8; m++){
        long long r = rowA + wm2 * 128 + m * 16 + kgrp * 4;
        #pragma unroll
        for (int j = 0; j < 4; j++){
          long long o = (r + j) * ldc + col;
          cf[o] = acc[m][n][j] + cf[o];     // residual: read V then overwrite
        }
      }
    }
  }
}

// x fp32 -> f16 plane
__global__ __launch_bounds__(256)
void prep_x(const float* __restrict__ X, u16* __restrict__ Xh)
{
  const long long n8 = (long long)NTOT * HD / 8;
  for (long long i = (long long)blockIdx.x * 256 + threadIdx.x; i < n8;
       i += (long long)gridDim.x * 256){
    const float* p = X + i * 8;
    float4 a = *(const float4*)p;
    float4 b = *(const float4*)(p + 4);
    float f[8] = {a.x, a.y, a.z, a.w, b.x, b.y, b.z, b.w};
    s16x8 h;
    #pragma unroll
    for (int j = 0; j < 8; j++) h[j] = (short)f2h(f[j]);
    *(s16x8*)&Xh[i * 8] = h;
  }
}

// W[k][n] -> transposed f16 Wt[z][n][k]
__global__ void prep_w(const float* __restrict__ Wq, const float* __restrict__ Wk,
                       const float* __restrict__ Wv, u16* __restrict__ Wt)
{
  __shared__ float t[32][33];
  const float* Win = (blockIdx.z == 0) ? Wq : (blockIdx.z == 1) ? Wk : Wv;
  const size_t zo = (size_t)blockIdx.z * HD * HD;
  int n0 = blockIdx.x * 32, k0 = blockIdx.y * 32;
  int tx = threadIdx.x, ty = threadIdx.y;
  #pragma unroll
  for (int i = 0; i < 4; i++)
    t[ty + 8*i][tx] = Win[(size_t)(k0 + ty + 8*i) * HD + n0 + tx];
  __syncthreads();
  #pragma unroll
  for (int i = 0; i < 4; i++)
    Wt[zo + (size_t)(n0 + ty + 8*i) * HD + k0 + tx] = f2h(t[tx][ty + 8*i]);
}

// softmax over compact triangular SC (256^2 tiles) -> compact P (f16)
__global__ __launch_bounds__(256)
void softmax_causal(const float* __restrict__ SC, u16* __restrict__ P)
{
  const int s = blockIdx.x;
  const int i = s >> 8;                 // 256-row tile
  const int tri = i * (i + 1) / 2;
  const long long base = (long long)blockIdx.y * CE + (long long)tri * 65536
                       + (long long)(s & 255) * 256;
  const float* scb = SC + base;
  u16* pb = P + base;

  __shared__ float buf[SQ];
  __shared__ float red[4];
  const int tid = threadIdx.x, lane = tid & 63, wid = tid >> 6;

  float m = -3.4e38f;
  for (int t = tid; t <= s; t += 256){
    float v = scb[(t >> 8) * 65536 + (t & 255)];
    buf[t] = v; m = fmaxf(m, v);
  }
  #pragma unroll
  for (int o = 32; o; o >>= 1) m = fmaxf(m, __shfl_xor(m, o));
  if (lane == 0) red[wid] = m;
  __syncthreads();
  m = fmaxf(fmaxf(red[0], red[1]), fmaxf(red[2], red[3]));
  __syncthreads();

  float sum = 0.f;
  for (int t = tid; t <= s; t += 256){ float e = __expf(buf[t] - m); buf[t] = e; sum += e; }
  #pragma unroll
  for (int o = 32; o; o >>= 1) sum += __shfl_xor(sum, o);
  if (lane == 0) red[wid] = sum;
  __syncthreads();
  sum = red[0] + red[1] + red[2] + red[3];
  const float inv = 1.f / sum;

  const int lim = (i + 1) << 8;         // PV reads keys < (i+1)*256
  for (int t = tid; t < lim; t += 256)
    pb[(t >> 8) * 65536 + (t & 255)] = (t <= s) ? f2h(buf[t] * inv) : (u16)0;
}

__global__ __launch_bounds__(256)
void layernorm_inplace(float* __restrict__ Y, const float* __restrict__ gamma,
                       const float* __restrict__ beta)
{
  float* y = Y + (long long)blockIdx.x * HD;
  const int tid = threadIdx.x, lane = tid & 63, wid = tid >> 6;
  float xv[4];
  float s = 0.f, ss = 0.f;
  #pragma unroll
  for (int i = 0; i < 4; i++){
    float v = y[tid + i * 256];
    xv[i] = v; s += v; ss += v * v;
  }
  #pragma unroll
  for (int o = 32; o; o >>= 1){ s += __shfl_xor(s, o); ss += __shfl_xor(ss, o); }
  __shared__ float r1[4], r2[4];
  if (lane == 0){ r1[wid] = s; r2[wid] = ss; }
  __syncthreads();
  s  = r1[0] + r1[1] + r1[2] + r1[3];
  ss = r2[0] + r2[1] + r2[2] + r2[3];
  const float mu   = s * (1.f / HD);
  const float var  = ss * (1.f / HD) - mu * mu;
  const float rstd = rsqrtf(var + 1e-5f);
  #pragma unroll
  for (int i = 0; i < 4; i++){
    int c = tid + i * 256;
    y[c] = (xv[i] - mu) * rstd * gamma[c] + beta[c];
  }
}

extern "C" void kernel_launch(void* const* d_in, const int* in_sizes, int n_in,
                              void* d_out, int out_size, void* d_ws, size_t ws_size,
                              hipStream_t stream)
{
  const float* x     = (const float*)d_in[0];
  const float* Wq    = (const float*)d_in[1];
  const float* bq    = (const float*)d_in[2];
  const float* Wk    = (const float*)d_in[3];
  const float* bk    = (const float*)d_in[4];
  const float* Wv    = (const float*)d_in[5];
  const float* bv    = (const float*)d_in[6];
  const float* gamma = (const float*)d_in[7];
  const float* beta  = (const float*)d_in[8];
  float* out = (float*)d_out;

  char* wsp = (char*)d_ws;
  size_t off = 0;
  auto alloc = [&](size_t bytes) -> char* {
    char* p = wsp + off;
    off = (off + bytes + 255) & ~(size_t)255;
    return p;
  };

  u16* Wt = (u16*)alloc(3ULL * HD * HD * 2);          // 6.3 MB  (transposed f16)
  u16* QK = (u16*)alloc(2ULL * NTOT * HD * 2);        // 67.1 MB (Q plane, K plane)
  u16* Vt = (u16*)alloc((size_t)NB * HD * SQ * 2);    // 33.6 MB (V transposed f16)

  // region: xh (phase A) aliased with compact SC/P (phase B)
  size_t rem = (ws_size > off) ? (ws_size - off) : 0;
  size_t perb = (size_t)CE * 6;                       // SC f32 + P f16 per batch
  int G = (int)(rem / perb);
  if (G > NB) G = NB;
  if (G < 1)  G = 1;
  u16*   xh = (u16*)(wsp + off);                      // 33.5 MB
  float* SC = (float*)(wsp + off);                    // G * 9.4 MB (compact)
  u16*   P  = (u16*)(wsp + off + (size_t)G * CE * 4); // G * 4.7 MB (compact)

  u16* Qh = QK;
  u16* Kh = QK + (size_t)NTOT * HD;
  float* V = out;   // V fp32 lives in d_out; PV reads V[o] then overwrites o

  prep_x<<<dim3(2048), dim3(256), 0, stream>>>(x, xh);
  prep_w<<<dim3(HD/32, HD/32, 3), dim3(32, 8), 0, stream>>>(Wq, Wk, Wv, Wt);

  // QKV projection: z=0 -> Q f16, z=1 -> K f16, z=2 -> V fp32(d_out) + Vt f16
  gemm8<0><<<dim3(NTOT/256, HD/256, 3), 512, 0, stream>>>(
      xh, Wt, V, QK, Vt, bq, bk, bv,
      HD, HD, HD, HD,
      0LL, (long long)HD * HD, (long long)NTOT * HD);

  for (int g0 = 0; g0 < NB; g0 += G){
    int g = (G < NB - g0) ? G : (NB - g0);
    // scores: triangular compact, 36 tiles of 256x256 per batch
    gemm8<1><<<dim3(NTRI2, 1, g), 512, 0, stream>>>(
        Qh + (size_t)g0 * SQ * HD, Kh + (size_t)g0 * SQ * HD,
        SC, nullptr, nullptr, nullptr, nullptr, nullptr,
        HD, HD, HD, 256,
        (long long)SQ * HD, (long long)SQ * HD, CE);
    softmax_causal<<<dim3(SQ, g), 256, 0, stream>>>(SC, P);
    // PV + residual; A = compact P
    gemm8<2><<<dim3(NT2, HD/256, g), 512, 0, stream>>>(
        P, Vt + (size_t)g0 * HD * SQ,
        out + (size_t)g0 * SQ * HD, nullptr, nullptr, nullptr, nullptr, nullptr,
        SQ, 256, SQ, HD,
        CE, (long long)HD * SQ, (long long)SQ * HD);
  }

  layernorm_inplace<<<dim3(NTOT), 256, 0, stream>>>(out, gamma, beta);
}